// Round 7
// baseline (1117.436 us; speedup 1.0000x reference)
//
#include <hip/hip_runtime.h>
#include <math.h>

// Problem constants (B=8 batches, N=M=2048 points, D=3)
#define BATCH 8
#define NPTS 2048
#define THREADS 512            // 8 waves
#define HALF_COLS 1024         // columns staged per LDS stage
#define NTILES_H 64            // MFMA tiles per stage (1024/16)
#define ROWS_PER_WAVE 16       // FRAGS=1: one A-frag per wave
#define ROWS_PER_BLOCK 128     // 8 waves * 16 rows
#define RTHREADS 256
#define LOG_M 7.62559580411076 // log(2048)

typedef __attribute__((ext_vector_type(8))) __bf16 bf16x8;
typedef __attribute__((ext_vector_type(4))) float f32x4;

union FragU { unsigned short u[8]; uint4 v; };

__device__ __forceinline__ unsigned short f2bf(float f) {
    union { float f; unsigned u; } x; x.f = f;
    unsigned r = x.u + 0x7FFFu + ((x.u >> 16) & 1u);   // RNE
    return (unsigned short)(r >> 16);
}
__device__ __forceinline__ float bf2f(unsigned short b) {
    union { unsigned u; float f; } x; x.u = ((unsigned)b) << 16;
    return x.f;
}

// Single-pass softmin via MFMA with estimated LSE shift (no max pass).
//   arg_ij = (x'_i . y'_j + pot_j - 0.5|y'_j|^2) * log2(e)/eps  (log2 domain)
// via mfma_f32_16x16x32_bf16: 2-way bf16 splits of sigma*x' and y', 3-way
// split of sigma*hhe, k16-31 dup k0-15 (acc=2*sigma*v, sigma=log2e/(2eps)).
// Shift m2_hat = (rowconst - old)/k2 enters as the MFMA C operand;
// res = old - k2*log2(s) (rowconst cancels); shift est is ~44 log2 units
// from true max worst-case, inside f32's ~116-unit range slack.
// Round 7: 16 rows/wave, 8 waves/block, BF halved to 1024 cols restaged
// once mid-kernel -> 36.5 KB LDS, 2 blocks/CU, 16 waves/CU = 4 waves/SIMD
// (was 2); MFMA->exp2 software-pipelined (consume tile t while t+1's MFMA
// is in flight). Per-entry cost: 1 exp2 + 1 add (trans-pipe floor 6.8 us).
// C layout (verified): col=lane&15, row=(lane>>4)*4+reg.
__global__ __launch_bounds__(THREADS, 4) void softmin_pass(
    const float* __restrict__ x, const float* __restrict__ y,
    const float* __restrict__ potSrc, float* __restrict__ potDst,
    float sigma, float k2, float inv_k2, float rowc0, int avg)
{
    __shared__ uint4 BF[NTILES_H][32];    // 32 KB: B fragments (one half)
    __shared__ uint4 AF[8][32];           //  4 KB: A fragments (8 waves)
    __shared__ float NM[ROWS_PER_BLOCK];  // -m2_hat per row

    const int type  = blockIdx.z;
    const int batch = blockIdx.y;

    const float* rowP;
    const float* colP;
    int hslot, oslot;
    if (type == 0)      { rowP = x; colP = y; hslot = 1; oslot = 0; }  // f_ba
    else if (type == 1) { rowP = y; colP = x; hslot = 0; oslot = 1; }  // g_ab
    else if (type == 2) { rowP = x; colP = x; hslot = 2; oslot = 2; }  // f_aa
    else                { rowP = y; colP = y; hslot = 3; oslot = 3; }  // g_bb

    rowP += batch * NPTS * 3;
    colP += batch * NPTS * 3;
    const float* hP   = potSrc + (hslot * BATCH + batch) * NPTS;
    const float* oldP = potSrc + (oslot * BATCH + batch) * NPTS;
    float*       outP = potDst + (oslot * BATCH + batch) * NPTS;

    // ---- B-fragment staging for column half h (1024 cols) ----
    auto stageB = [&](int h) {
        for (int jj = threadIdx.x; jj < HALF_COLS; jj += THREADS) {  // 2 iters
            const int j = h * HALF_COLS + jj;
            float y0 = colP[3 * j + 0], y1 = colP[3 * j + 1], y2 = colP[3 * j + 2];
            float p0 = y0 - 0.5f, p1 = y1 - 0.5f, p2 = y2 - 0.5f;
            unsigned short h0 = f2bf(p0); unsigned short l0 = f2bf(p0 - bf2f(h0));
            unsigned short h1 = f2bf(p1); unsigned short l1 = f2bf(p1 - bf2f(h1));
            unsigned short h2 = f2bf(p2); unsigned short l2 = f2bf(p2 - bf2f(h2));
            float hhe = sigma * (hP[j] - 0.5f * (p0 * p0 + p1 * p1 + p2 * p2));
            unsigned short hA = f2bf(hhe); float r1 = hhe - bf2f(hA);
            unsigned short hB = f2bf(r1);  float r2 = r1 - bf2f(hB);
            unsigned short hC = f2bf(r2);
            FragU f0, f1;
            f0.u[0] = h0; f0.u[1] = l0; f0.u[2] = h0; f0.u[3] = l0;
            f0.u[4] = h1; f0.u[5] = l1; f0.u[6] = h1; f0.u[7] = l1;
            f1.u[0] = h2; f1.u[1] = l2; f1.u[2] = h2; f1.u[3] = l2;
            f1.u[4] = hA; f1.u[5] = hB; f1.u[6] = hC; f1.u[7] = 0;
            BF[jj >> 4][jj & 15]        = f0.v;   // k0-7 half  (quads 0,2)
            BF[jj >> 4][16 + (jj & 15)] = f1.v;   // k8-15 half (quads 1,3)
        }
    };

    // ---- stage A fragments (8 waves x 32 slots = 256 threads) ----
    if (threadIdx.x < 256) {
        const int t = threadIdx.x;
        const int w = t >> 5, idx = t & 31;
        const int row = blockIdx.x * ROWS_PER_BLOCK + w * ROWS_PER_WAVE + (idx & 15);
        float x0 = rowP[3 * row + 0], x1 = rowP[3 * row + 1], x2 = rowP[3 * row + 2];
        float p0 = sigma * (x0 - 0.5f), p1 = sigma * (x1 - 0.5f), p2 = sigma * (x2 - 0.5f);
        unsigned short h0 = f2bf(p0); unsigned short l0 = f2bf(p0 - bf2f(h0));
        unsigned short h1 = f2bf(p1); unsigned short l1 = f2bf(p1 - bf2f(h1));
        unsigned short h2 = f2bf(p2); unsigned short l2 = f2bf(p2 - bf2f(h2));
        FragU f;
        if (idx < 16) {   // k0-7
            f.u[0] = h0; f.u[1] = h0; f.u[2] = l0; f.u[3] = l0;
            f.u[4] = h1; f.u[5] = h1; f.u[6] = l1; f.u[7] = l1;
        } else {          // k8-15
            f.u[0] = h2; f.u[1] = h2; f.u[2] = l2; f.u[3] = l2;
            f.u[4] = 0x3F80; f.u[5] = 0x3F80; f.u[6] = 0x3F80; f.u[7] = 0;
        }
        AF[w][idx] = f.v;
    } else if (threadIdx.x < 256 + ROWS_PER_BLOCK) {
        // ---- stage per-row shift: NM[r] = (old - rowconst)/k2 = -m2_hat ----
        const int r = threadIdx.x - 256;
        const int i = blockIdx.x * ROWS_PER_BLOCK + r;
        float x0 = rowP[3 * i + 0], x1 = rowP[3 * i + 1], x2 = rowP[3 * i + 2];
        float p0 = x0 - 0.5f, p1 = x1 - 0.5f, p2 = x2 - 0.5f;
        float rowconst = 0.5f * (p0 * p0 + p1 * p1 + p2 * p2) + rowc0;
        NM[r] = (oldP[i] - rowconst) * inv_k2;
    }
    stageB(0);
    __syncthreads();

    const int lane = threadIdx.x & 63;
    const int wave = threadIdx.x >> 6;
    const int lidx = lane & 31;
    const int quad = lane >> 4;

    const bf16x8 af = *(const bf16x8*)&AF[wave][lidx];
    const f32x4 nm = *(const f32x4*)&NM[wave * ROWS_PER_WAVE + quad * 4];

    float s[4] = {0.0f, 0.0f, 0.0f, 0.0f};

    // ---- half 0: software-pipelined MFMA -> exp2 ----
    {
        f32x4 ap = __builtin_amdgcn_mfma_f32_16x16x32_bf16(
                       af, *(const bf16x8*)&BF[0][lidx], nm, 0, 0, 0);
        #pragma unroll 4
        for (int t = 1; t < NTILES_H; ++t) {
            f32x4 an = __builtin_amdgcn_mfma_f32_16x16x32_bf16(
                           af, *(const bf16x8*)&BF[t][lidx], nm, 0, 0, 0);
            #pragma unroll
            for (int r = 0; r < 4; ++r) s[r] += __builtin_amdgcn_exp2f(ap[r]);
            ap = an;
        }
        #pragma unroll
        for (int r = 0; r < 4; ++r) s[r] += __builtin_amdgcn_exp2f(ap[r]);
    }

    __syncthreads();   // all waves done reading half 0
    stageB(1);
    __syncthreads();   // half 1 staged

    // ---- half 1 ----
    {
        f32x4 ap = __builtin_amdgcn_mfma_f32_16x16x32_bf16(
                       af, *(const bf16x8*)&BF[0][lidx], nm, 0, 0, 0);
        #pragma unroll 4
        for (int t = 1; t < NTILES_H; ++t) {
            f32x4 an = __builtin_amdgcn_mfma_f32_16x16x32_bf16(
                           af, *(const bf16x8*)&BF[t][lidx], nm, 0, 0, 0);
            #pragma unroll
            for (int r = 0; r < 4; ++r) s[r] += __builtin_amdgcn_exp2f(ap[r]);
            ap = an;
        }
        #pragma unroll
        for (int r = 0; r < 4; ++r) s[r] += __builtin_amdgcn_exp2f(ap[r]);
    }

    // ---- reduce across the 16 cols within each quad-row group ----
    #pragma unroll
    for (int off = 1; off <= 8; off <<= 1)
        #pragma unroll
        for (int r = 0; r < 4; ++r)
            s[r] += __shfl_xor(s[r], off, 64);

    // ---- epilogue: res = old - k2*log2(s); col==0 lanes write 4 rows ----
    if ((lane & 15) == 0) {
        #pragma unroll
        for (int r = 0; r < 4; ++r) {
            const int i = blockIdx.x * ROWS_PER_BLOCK + wave * ROWS_PER_WAVE
                        + quad * 4 + r;
            float oldv = oldP[i];
            float res = oldv - k2 * __log2f(s[r]);
            outP[i] = avg ? 0.5f * (oldv + res) : res;
        }
    }
}

// out[b] = (1/N) * sum_i (f_ba - f_aa) + (1/M) * sum_j (g_ab - g_bb)
__global__ void reduce_out(const float* __restrict__ pot, float* __restrict__ out)
{
    const int batch = blockIdx.x;
    const float* fba = pot + (0 * BATCH + batch) * NPTS;
    const float* gab = pot + (1 * BATCH + batch) * NPTS;
    const float* faa = pot + (2 * BATCH + batch) * NPTS;
    const float* gbb = pot + (3 * BATCH + batch) * NPTS;

    float s = 0.0f;
    for (int i = threadIdx.x; i < NPTS; i += blockDim.x)
        s += (fba[i] - faa[i]) + (gab[i] - gbb[i]);

    #pragma unroll
    for (int off = 32; off >= 1; off >>= 1)
        s += __shfl_xor(s, off, 64);

    __shared__ float red[RTHREADS / 64];
    const int lane = threadIdx.x & 63;
    const int wave = threadIdx.x >> 6;
    if (lane == 0) red[wave] = s;
    __syncthreads();
    if (threadIdx.x == 0) {
        float t = 0.0f;
        for (int w = 0; w < RTHREADS / 64; ++w) t += red[w];
        out[batch] = t * (1.0f / NPTS);
    }
}

extern "C" void kernel_launch(void* const* d_in, const int* in_sizes, int n_in,
                              void* d_out, int out_size, void* d_ws, size_t ws_size,
                              hipStream_t stream)
{
    const float* x = (const float*)d_in[0];
    const float* y = (const float*)d_in[1];
    float* out = (float*)d_out;

    // Ping-pong potential buffers in workspace: [4 slots][B][NPTS] each.
    const size_t potElems = (size_t)4 * BATCH * NPTS;
    float* P0 = (float*)d_ws;
    float* P1 = P0 + potElems;

    // Zero the initial potentials (h = a_log exactly at init; old = 0).
    hipMemsetAsync(P0, 0, potElems * sizeof(float), stream);

    // Epsilon schedule: [diam^p] + exp(arange(p ln diam, p ln blur, p ln scale)) + [blur^p]
    double epsl[16];
    int ne = 0;
    epsl[ne++] = 4.0;                       // diameter^2
    const double stop = 2.0 * log(0.05);
    const double step = 2.0 * log(0.5);
    for (double e = 2.0 * log(2.0); e > stop; e += step)
        epsl[ne++] = exp(e);                // 4, 1, 0.25, 0.0625, 0.015625, 0.00390625
    epsl[ne++] = 0.05 * 0.05;               // blur^2 = 0.0025

    float* src = P0;
    float* dst = P1;
    dim3 grid(NPTS / ROWS_PER_BLOCK, BATCH, 4);

    auto launch = [&](double eps, int avg) {
        float sigma  = (float)(M_LOG2E / (2.0 * eps));  // k-dup doubling folded in
        float k2     = (float)(eps * M_LN2);
        float inv_k2 = (float)(1.0 / (eps * M_LN2));
        float rowc0  = (float)(eps * LOG_M);
        softmin_pass<<<grid, THREADS, 0, stream>>>(
            x, y, src, dst, sigma, k2, inv_k2, rowc0, avg);
        float* t = src; src = dst; dst = t;
    };

    launch(epsl[0], 0);                       // init (writes direct)
    for (int k = 0; k < ne; ++k)
        launch(epsl[k], 1);                   // damped symmetric Sinkhorn
    launch(epsl[ne - 1], 0);                  // final extrapolation (writes direct)

    reduce_out<<<dim3(BATCH), RTHREADS, 0, stream>>>(src, out);
}

// Round 8
// 284.620 us; speedup vs baseline: 3.9261x; 3.9261x over previous
//
#include <hip/hip_runtime.h>
#include <math.h>

// Problem constants (B=8 batches, N=M=2048 points, D=3)
#define BATCH 8
#define NPTS 2048
#define THREADS 256
#define HALF_COLS 1024         // columns staged per LDS stage
#define NTILES_H 64            // MFMA tiles per stage (1024/16)
#define FRAGS 2                // A fragments (16 rows each) per wave
#define ROWS_PER_WAVE 32
#define ROWS_PER_BLOCK 128     // 4 waves
#define LOG_M 7.62559580411076 // log(2048)

typedef __attribute__((ext_vector_type(8))) __bf16 bf16x8;
typedef __attribute__((ext_vector_type(4))) float f32x4;

union FragU { unsigned short u[8]; uint4 v; };

__device__ __forceinline__ unsigned short f2bf(float f) {
    union { float f; unsigned u; } x; x.f = f;
    unsigned r = x.u + 0x7FFFu + ((x.u >> 16) & 1u);   // RNE
    return (unsigned short)(r >> 16);
}
__device__ __forceinline__ float bf2f(unsigned short b) {
    union { unsigned u; float f; } x; x.u = ((unsigned)b) << 16;
    return x.f;
}

// Single-pass softmin via MFMA with estimated LSE shift (no max pass).
//   arg_ij = (x'_i . y'_j + pot_j - 0.5|y'_j|^2) * log2(e)/eps  (log2 domain)
// via mfma_f32_16x16x32_bf16: 2-way bf16 splits of sigma*x' and y', 3-way
// split of sigma*hhe, k16-31 dup k0-15 (acc=2*sigma*v, sigma=log2e/(2eps)).
// Shift m2_hat = (rowconst - old)/k2 enters as the MFMA C operand;
// res = old - k2*log2(s) (rowconst cancels); shift is ~44 log2 units from
// the true max worst-case, inside f32's ~116-unit range slack.
// Round 8: r6 structure (256 thr, FRAGS=2, no launch_bounds min-arg: the
// r7 min-occupancy arg caused loop-interior scratch spill = 161 MB/dispatch)
// with BF halved to 1024 cols restaged once -> 36.5 KB LDS -> 4 blocks/CU
// = 16 waves/CU = 4 waves/SIMD (r6 had 2). Summation order identical to r6.
// C layout (verified): col=lane&15, row=(lane>>4)*4+reg.
__global__ __launch_bounds__(THREADS) void softmin_pass(
    const float* __restrict__ x, const float* __restrict__ y,
    const float* __restrict__ potSrc, float* __restrict__ potDst,
    float sigma, float k2, float inv_k2, float rowc0, int avg)
{
    __shared__ uint4 BF[NTILES_H][32];    // 32 KB: B fragments (one half)
    __shared__ uint4 AF[4][FRAGS][32];    //  4 KB: A fragments
    __shared__ float NM[ROWS_PER_BLOCK];  // -m2_hat per row

    const int type  = blockIdx.z;
    const int batch = blockIdx.y;

    const float* rowP;
    const float* colP;
    int hslot, oslot;
    if (type == 0)      { rowP = x; colP = y; hslot = 1; oslot = 0; }  // f_ba
    else if (type == 1) { rowP = y; colP = x; hslot = 0; oslot = 1; }  // g_ab
    else if (type == 2) { rowP = x; colP = x; hslot = 2; oslot = 2; }  // f_aa
    else                { rowP = y; colP = y; hslot = 3; oslot = 3; }  // g_bb

    rowP += batch * NPTS * 3;
    colP += batch * NPTS * 3;
    const float* hP   = potSrc + (hslot * BATCH + batch) * NPTS;
    const float* oldP = potSrc + (oslot * BATCH + batch) * NPTS;
    float*       outP = potDst + (oslot * BATCH + batch) * NPTS;

    // ---- stage A fragments: 4 waves x 2 frags x 32 slots = 256 threads ----
    {
        const int t = threadIdx.x;
        const int w = t >> 6, fr = (t >> 5) & 1, idx = t & 31;
        const int row = blockIdx.x * ROWS_PER_BLOCK + w * ROWS_PER_WAVE
                      + fr * 16 + (idx & 15);
        float x0 = rowP[3 * row + 0], x1 = rowP[3 * row + 1], x2 = rowP[3 * row + 2];
        float p0 = sigma * (x0 - 0.5f), p1 = sigma * (x1 - 0.5f), p2 = sigma * (x2 - 0.5f);
        unsigned short h0 = f2bf(p0); unsigned short l0 = f2bf(p0 - bf2f(h0));
        unsigned short h1 = f2bf(p1); unsigned short l1 = f2bf(p1 - bf2f(h1));
        unsigned short h2 = f2bf(p2); unsigned short l2 = f2bf(p2 - bf2f(h2));
        FragU f;
        if (idx < 16) {   // k0-7
            f.u[0] = h0; f.u[1] = h0; f.u[2] = l0; f.u[3] = l0;
            f.u[4] = h1; f.u[5] = h1; f.u[6] = l1; f.u[7] = l1;
        } else {          // k8-15
            f.u[0] = h2; f.u[1] = h2; f.u[2] = l2; f.u[3] = l2;
            f.u[4] = 0x3F80; f.u[5] = 0x3F80; f.u[6] = 0x3F80; f.u[7] = 0;
        }
        AF[w][fr][idx] = f.v;
    }

    // ---- stage per-row shift: NM[r] = (old - rowconst)/k2 = -m2_hat ----
    if (threadIdx.x < ROWS_PER_BLOCK) {
        const int i = blockIdx.x * ROWS_PER_BLOCK + threadIdx.x;
        float x0 = rowP[3 * i + 0], x1 = rowP[3 * i + 1], x2 = rowP[3 * i + 2];
        float p0 = x0 - 0.5f, p1 = x1 - 0.5f, p2 = x2 - 0.5f;
        float rowconst = 0.5f * (p0 * p0 + p1 * p1 + p2 * p2) + rowc0;
        NM[threadIdx.x] = (oldP[i] - rowconst) * inv_k2;
    }

    const int lane = threadIdx.x & 63;
    const int wave = threadIdx.x >> 6;
    const int lidx = lane & 31;
    const int quad = lane >> 4;

    float s[FRAGS][4] = {{0,0,0,0},{0,0,0,0}};
    bf16x8 af0, af1;
    f32x4 nm0, nm1;

    // ---- two column halves, BF restaged between them ----
    for (int h = 0; h < 2; ++h) {
        if (h) __syncthreads();   // all waves done reading previous half

        // stage B fragments for this half (4 iters of 256 threads)
        for (int jj = threadIdx.x; jj < HALF_COLS; jj += THREADS) {
            const int j = h * HALF_COLS + jj;
            float y0 = colP[3 * j + 0], y1 = colP[3 * j + 1], y2 = colP[3 * j + 2];
            float p0 = y0 - 0.5f, p1 = y1 - 0.5f, p2 = y2 - 0.5f;
            unsigned short h0 = f2bf(p0); unsigned short l0 = f2bf(p0 - bf2f(h0));
            unsigned short h1 = f2bf(p1); unsigned short l1 = f2bf(p1 - bf2f(h1));
            unsigned short h2 = f2bf(p2); unsigned short l2 = f2bf(p2 - bf2f(h2));
            float hhe = sigma * (hP[j] - 0.5f * (p0 * p0 + p1 * p1 + p2 * p2));
            unsigned short hA = f2bf(hhe); float r1 = hhe - bf2f(hA);
            unsigned short hB = f2bf(r1);  float r2 = r1 - bf2f(hB);
            unsigned short hC = f2bf(r2);
            FragU f0, f1;
            f0.u[0] = h0; f0.u[1] = l0; f0.u[2] = h0; f0.u[3] = l0;
            f0.u[4] = h1; f0.u[5] = l1; f0.u[6] = h1; f0.u[7] = l1;
            f1.u[0] = h2; f1.u[1] = l2; f1.u[2] = h2; f1.u[3] = l2;
            f1.u[4] = hA; f1.u[5] = hB; f1.u[6] = hC; f1.u[7] = 0;
            BF[jj >> 4][jj & 15]        = f0.v;   // k0-7 half  (quads 0,2)
            BF[jj >> 4][16 + (jj & 15)] = f1.v;   // k8-15 half (quads 1,3)
        }
        __syncthreads();

        if (h == 0) {   // A-frags / NM ready after first barrier
            af0 = *(const bf16x8*)&AF[wave][0][lidx];
            af1 = *(const bf16x8*)&AF[wave][1][lidx];
            nm0 = *(const f32x4*)&NM[wave * ROWS_PER_WAVE + quad * 4];
            nm1 = *(const f32x4*)&NM[wave * ROWS_PER_WAVE + 16 + quad * 4];
        }

        // s += sum over this half's tiles of 2^(arg - m2_hat)
        #pragma unroll 4
        for (int t = 0; t < NTILES_H; ++t) {
            bf16x8 bf = *(const bf16x8*)&BF[t][lidx];
            f32x4 a0 = __builtin_amdgcn_mfma_f32_16x16x32_bf16(af0, bf, nm0, 0, 0, 0);
            f32x4 a1 = __builtin_amdgcn_mfma_f32_16x16x32_bf16(af1, bf, nm1, 0, 0, 0);
            #pragma unroll
            for (int r = 0; r < 4; ++r) {
                s[0][r] += __builtin_amdgcn_exp2f(a0[r]);
                s[1][r] += __builtin_amdgcn_exp2f(a1[r]);
            }
        }
    }

    // ---- reduce across the 16 cols within each quad-row group ----
    #pragma unroll
    for (int off = 1; off <= 8; off <<= 1)
        #pragma unroll
        for (int f = 0; f < FRAGS; ++f)
            #pragma unroll
            for (int r = 0; r < 4; ++r)
                s[f][r] += __shfl_xor(s[f][r], off, 64);

    // ---- epilogue: res = old - k2*log2(s); col==0 lanes write 8 rows ----
    if ((lane & 15) == 0) {
        #pragma unroll
        for (int f = 0; f < FRAGS; ++f) {
            #pragma unroll
            for (int r = 0; r < 4; ++r) {
                const int i = blockIdx.x * ROWS_PER_BLOCK + wave * ROWS_PER_WAVE
                            + f * 16 + quad * 4 + r;
                float oldv = oldP[i];
                float res = oldv - k2 * __log2f(s[f][r]);
                outP[i] = avg ? 0.5f * (oldv + res) : res;
            }
        }
    }
}

// out[b] = (1/N) * sum_i (f_ba - f_aa) + (1/M) * sum_j (g_ab - g_bb)
__global__ void reduce_out(const float* __restrict__ pot, float* __restrict__ out)
{
    const int batch = blockIdx.x;
    const float* fba = pot + (0 * BATCH + batch) * NPTS;
    const float* gab = pot + (1 * BATCH + batch) * NPTS;
    const float* faa = pot + (2 * BATCH + batch) * NPTS;
    const float* gbb = pot + (3 * BATCH + batch) * NPTS;

    float s = 0.0f;
    for (int i = threadIdx.x; i < NPTS; i += blockDim.x)
        s += (fba[i] - faa[i]) + (gab[i] - gbb[i]);

    #pragma unroll
    for (int off = 32; off >= 1; off >>= 1)
        s += __shfl_xor(s, off, 64);

    __shared__ float red[THREADS / 64];
    const int lane = threadIdx.x & 63;
    const int wave = threadIdx.x >> 6;
    if (lane == 0) red[wave] = s;
    __syncthreads();
    if (threadIdx.x == 0) {
        float t = 0.0f;
        for (int w = 0; w < THREADS / 64; ++w) t += red[w];
        out[batch] = t * (1.0f / NPTS);
    }
}

extern "C" void kernel_launch(void* const* d_in, const int* in_sizes, int n_in,
                              void* d_out, int out_size, void* d_ws, size_t ws_size,
                              hipStream_t stream)
{
    const float* x = (const float*)d_in[0];
    const float* y = (const float*)d_in[1];
    float* out = (float*)d_out;

    // Ping-pong potential buffers in workspace: [4 slots][B][NPTS] each.
    const size_t potElems = (size_t)4 * BATCH * NPTS;
    float* P0 = (float*)d_ws;
    float* P1 = P0 + potElems;

    // Zero the initial potentials (h = a_log exactly at init; old = 0).
    hipMemsetAsync(P0, 0, potElems * sizeof(float), stream);

    // Epsilon schedule: [diam^p] + exp(arange(p ln diam, p ln blur, p ln scale)) + [blur^p]
    double epsl[16];
    int ne = 0;
    epsl[ne++] = 4.0;                       // diameter^2
    const double stop = 2.0 * log(0.05);
    const double step = 2.0 * log(0.5);
    for (double e = 2.0 * log(2.0); e > stop; e += step)
        epsl[ne++] = exp(e);                // 4, 1, 0.25, 0.0625, 0.015625, 0.00390625
    epsl[ne++] = 0.05 * 0.05;               // blur^2 = 0.0025

    float* src = P0;
    float* dst = P1;
    dim3 grid(NPTS / ROWS_PER_BLOCK, BATCH, 4);

    auto launch = [&](double eps, int avg) {
        float sigma  = (float)(M_LOG2E / (2.0 * eps));  // k-dup doubling folded in
        float k2     = (float)(eps * M_LN2);
        float inv_k2 = (float)(1.0 / (eps * M_LN2));
        float rowc0  = (float)(eps * LOG_M);
        softmin_pass<<<grid, THREADS, 0, stream>>>(
            x, y, src, dst, sigma, k2, inv_k2, rowc0, avg);
        float* t = src; src = dst; dst = t;
    };

    launch(epsl[0], 0);                       // init (writes direct)
    for (int k = 0; k < ne; ++k)
        launch(epsl[k], 1);                   // damped symmetric Sinkhorn
    launch(epsl[ne - 1], 0);                  // final extrapolation (writes direct)

    reduce_out<<<dim3(BATCH), THREADS, 0, stream>>>(src, out);
}

// Round 9
// 268.092 us; speedup vs baseline: 4.1681x; 1.0617x over previous
//
#include <hip/hip_runtime.h>
#include <math.h>

// Problem constants (B=8 batches, N=M=2048 points, D=3)
#define BATCH 8
#define NPTS 2048
#define THREADS 256            // 4 waves: 2 row-groups x 2 col-splits
#define HALF_COLS 1024         // columns staged per LDS stage
#define TILES_H 32             // 32-col MFMA tiles per staged half
#define ROWS_PER_BLOCK 64      // 2 row-groups of 32
#define LOG_M 7.62559580411076 // log(2048)

typedef __attribute__((ext_vector_type(8)))  __bf16 bf16x8;
typedef __attribute__((ext_vector_type(16))) float  f32x16;

union FragU { unsigned short u[8]; uint4 v; };

__device__ __forceinline__ unsigned short f2bf(float f) {
    union { float f; unsigned u; } x; x.f = f;
    unsigned r = x.u + 0x7FFFu + ((x.u >> 16) & 1u);   // RNE
    return (unsigned short)(r >> 16);
}
__device__ __forceinline__ float bf2f(unsigned short b) {
    union { unsigned u; float f; } x; x.u = ((unsigned)b) << 16;
    return x.f;
}

// Single-pass softmin via 32x32x16 MFMA with estimated LSE shift (no max pass).
//   arg_ij = (x'_i . y'_j + pot_j - 0.5|y'_j|^2) * log2(e)/eps  (log2 domain)
// K=16 slots: per dim d, k-slots (xh,xh,xl,xl)x(yh,yl,yh,yl) = 4 products
// (12 slots), 3-way split of sigma*hhe against 1.0 (3 slots), slot 15 zero.
// No k-duplication -> sigma = log2e/eps. Shift m2_hat = (rowconst - old)/k2
// enters as the MFMA C operand; res = old - k2*log2(s) (rowconst cancels);
// shift is ~44 log2 units off worst-case, inside f32's ~116-unit slack.
// Round 9: 32x32 tiles halve LDS reads & MFMA count; columns split across
// 2 waves per 32-row group (partials merged via LDS) -> 1024 blocks = 4/CU
// x 4 waves = 4 waves/SIMD (r8 had 2). 256 thr, NO launch_bounds min-arg
// (r7: it caused 161 MB/dispatch scratch spill).
// A/B layout: m(n)=lane&31, k=(lane>>5)*8+j.
// C/D layout (verified m74/m101): col=lane&31, row=(reg&3)+8*(reg>>2)+4*(lane>>5).
__global__ __launch_bounds__(THREADS) void softmin_pass(
    const float* __restrict__ x, const float* __restrict__ y,
    const float* __restrict__ potSrc, float* __restrict__ potDst,
    float sigma, float k2, float inv_k2, float rowc0, int avg)
{
    __shared__ uint4 BF[TILES_H][64];     // 32 KB: B frags (one half), slot=lane
    __shared__ uint4 AF[2][64];           //  2 KB: A frags (2 row-groups)
    __shared__ float NM[ROWS_PER_BLOCK];  // -m2_hat per row
    __shared__ float SRED[2][2][32];      // partial sums [group][colsplit][row]

    const int type  = blockIdx.z;
    const int batch = blockIdx.y;

    const float* rowP;
    const float* colP;
    int hslot, oslot;
    if (type == 0)      { rowP = x; colP = y; hslot = 1; oslot = 0; }  // f_ba
    else if (type == 1) { rowP = y; colP = x; hslot = 0; oslot = 1; }  // g_ab
    else if (type == 2) { rowP = x; colP = x; hslot = 2; oslot = 2; }  // f_aa
    else                { rowP = y; colP = y; hslot = 3; oslot = 3; }  // g_bb

    rowP += batch * NPTS * 3;
    colP += batch * NPTS * 3;
    const float* hP   = potSrc + (hslot * BATCH + batch) * NPTS;
    const float* oldP = potSrc + (oslot * BATCH + batch) * NPTS;
    float*       outP = potDst + (oslot * BATCH + batch) * NPTS;

    // ---- stage A fragments: 2 groups x 64 slots = threads 0..127 ----
    if (threadIdx.x < 128) {
        const int g = threadIdx.x >> 6, idx = threadIdx.x & 63;
        const int row = blockIdx.x * ROWS_PER_BLOCK + g * 32 + (idx & 31);
        float x0 = rowP[3 * row + 0], x1 = rowP[3 * row + 1], x2 = rowP[3 * row + 2];
        float p0 = sigma * (x0 - 0.5f), p1 = sigma * (x1 - 0.5f), p2 = sigma * (x2 - 0.5f);
        unsigned short h0 = f2bf(p0); unsigned short l0 = f2bf(p0 - bf2f(h0));
        unsigned short h1 = f2bf(p1); unsigned short l1 = f2bf(p1 - bf2f(h1));
        unsigned short h2 = f2bf(p2); unsigned short l2 = f2bf(p2 - bf2f(h2));
        FragU f;
        if (idx < 32) {   // k0-7: dim0 (xh,xh,xl,xl), dim1 (xh,xh,xl,xl)
            f.u[0] = h0; f.u[1] = h0; f.u[2] = l0; f.u[3] = l0;
            f.u[4] = h1; f.u[5] = h1; f.u[6] = l1; f.u[7] = l1;
        } else {          // k8-15: dim2 (xh,xh,xl,xl), 1,1,1, 0
            f.u[0] = h2; f.u[1] = h2; f.u[2] = l2; f.u[3] = l2;
            f.u[4] = 0x3F80; f.u[5] = 0x3F80; f.u[6] = 0x3F80; f.u[7] = 0;
        }
        AF[g][idx] = f.v;
    } else if (threadIdx.x < 128 + ROWS_PER_BLOCK) {
        // ---- per-row shift: NM[r] = (old - rowconst)/k2 = -m2_hat ----
        const int r = threadIdx.x - 128;
        const int i = blockIdx.x * ROWS_PER_BLOCK + r;
        float x0 = rowP[3 * i + 0], x1 = rowP[3 * i + 1], x2 = rowP[3 * i + 2];
        float p0 = x0 - 0.5f, p1 = x1 - 0.5f, p2 = x2 - 0.5f;
        float rowconst = 0.5f * (p0 * p0 + p1 * p1 + p2 * p2) + rowc0;
        NM[r] = (oldP[i] - rowconst) * inv_k2;
    }

    const int lane = threadIdx.x & 63;
    const int wave = threadIdx.x >> 6;
    const int g    = wave >> 1;        // row-group 0..1
    const int c    = wave & 1;         // col-split 0..1
    const int khalf = lane >> 5;

    float s[16];
    #pragma unroll
    for (int r = 0; r < 16; ++r) s[r] = 0.0f;
    bf16x8 af;
    f32x16 nmv;

    // ---- two column halves, BF restaged between them ----
    for (int h = 0; h < 2; ++h) {
        if (h) __syncthreads();   // all waves done reading previous half

        // stage B fragments for this half (1024 cols, all 256 threads)
        for (int jj = threadIdx.x; jj < HALF_COLS; jj += THREADS) {
            const int j = h * HALF_COLS + jj;
            float y0 = colP[3 * j + 0], y1 = colP[3 * j + 1], y2 = colP[3 * j + 2];
            float p0 = y0 - 0.5f, p1 = y1 - 0.5f, p2 = y2 - 0.5f;
            unsigned short h0 = f2bf(p0); unsigned short l0 = f2bf(p0 - bf2f(h0));
            unsigned short h1 = f2bf(p1); unsigned short l1 = f2bf(p1 - bf2f(h1));
            unsigned short h2 = f2bf(p2); unsigned short l2 = f2bf(p2 - bf2f(h2));
            float hhe = sigma * (hP[j] - 0.5f * (p0 * p0 + p1 * p1 + p2 * p2));
            unsigned short hA = f2bf(hhe); float r1 = hhe - bf2f(hA);
            unsigned short hB = f2bf(r1);  float r2 = r1 - bf2f(hB);
            unsigned short hC = f2bf(r2);
            FragU f0, f1;
            // k0-7: dim0 (yh,yl,yh,yl), dim1 (yh,yl,yh,yl)
            f0.u[0] = h0; f0.u[1] = l0; f0.u[2] = h0; f0.u[3] = l0;
            f0.u[4] = h1; f0.u[5] = l1; f0.u[6] = h1; f0.u[7] = l1;
            // k8-15: dim2 (yh,yl,yh,yl), hA,hB,hC, 0
            f1.u[0] = h2; f1.u[1] = l2; f1.u[2] = h2; f1.u[3] = l2;
            f1.u[4] = hA; f1.u[5] = hB; f1.u[6] = hC; f1.u[7] = 0;
            BF[jj >> 5][jj & 31]        = f0.v;   // k0-7  (lanes 0-31)
            BF[jj >> 5][32 + (jj & 31)] = f1.v;   // k8-15 (lanes 32-63)
        }
        __syncthreads();

        if (h == 0) {   // A-frags / NM ready after first barrier
            af = *(const bf16x8*)&AF[g][lane];
            #pragma unroll
            for (int r = 0; r < 16; ++r) {
                const int row = (r & 3) + 8 * (r >> 2) + 4 * khalf;
                nmv[r] = NM[g * 32 + row];
            }
        }

        // this wave's 16 tiles of the staged 32
        const int tbase = c * (TILES_H / 2);
        #pragma unroll 2
        for (int t = 0; t < TILES_H / 2; ++t) {
            bf16x8 bf = *(const bf16x8*)&BF[tbase + t][lane];
            f32x16 acc = __builtin_amdgcn_mfma_f32_32x32x16_bf16(af, bf, nmv, 0, 0, 0);
            #pragma unroll
            for (int r = 0; r < 16; ++r)
                s[r] += __builtin_amdgcn_exp2f(acc[r]);
        }
    }

    // ---- reduce over the 32 cols held across lanes (xor 1..16) ----
    #pragma unroll
    for (int off = 1; off <= 16; off <<= 1)
        #pragma unroll
        for (int r = 0; r < 16; ++r)
            s[r] += __shfl_xor(s[r], off, 64);

    // ---- write col-split partials; merge; epilogue ----
    if ((lane & 31) == 0) {
        #pragma unroll
        for (int r = 0; r < 16; ++r) {
            const int row = (r & 3) + 8 * (r >> 2) + 4 * khalf;
            SRED[g][c][row] = s[r];
        }
    }
    __syncthreads();

    if (threadIdx.x < ROWS_PER_BLOCK) {
        const int p = threadIdx.x >> 5, r = threadIdx.x & 31;
        const int i = blockIdx.x * ROWS_PER_BLOCK + p * 32 + r;
        float sum = SRED[p][0][r] + SRED[p][1][r];
        float oldv = oldP[i];
        float res = oldv - k2 * __log2f(sum);
        outP[i] = avg ? 0.5f * (oldv + res) : res;
    }
}

// out[b] = (1/N) * sum_i (f_ba - f_aa) + (1/M) * sum_j (g_ab - g_bb)
__global__ void reduce_out(const float* __restrict__ pot, float* __restrict__ out)
{
    const int batch = blockIdx.x;
    const float* fba = pot + (0 * BATCH + batch) * NPTS;
    const float* gab = pot + (1 * BATCH + batch) * NPTS;
    const float* faa = pot + (2 * BATCH + batch) * NPTS;
    const float* gbb = pot + (3 * BATCH + batch) * NPTS;

    float s = 0.0f;
    for (int i = threadIdx.x; i < NPTS; i += blockDim.x)
        s += (fba[i] - faa[i]) + (gab[i] - gbb[i]);

    #pragma unroll
    for (int off = 32; off >= 1; off >>= 1)
        s += __shfl_xor(s, off, 64);

    __shared__ float red[THREADS / 64];
    const int lane = threadIdx.x & 63;
    const int wave = threadIdx.x >> 6;
    if (lane == 0) red[wave] = s;
    __syncthreads();
    if (threadIdx.x == 0) {
        float t = 0.0f;
        for (int w = 0; w < THREADS / 64; ++w) t += red[w];
        out[batch] = t * (1.0f / NPTS);
    }
}

extern "C" void kernel_launch(void* const* d_in, const int* in_sizes, int n_in,
                              void* d_out, int out_size, void* d_ws, size_t ws_size,
                              hipStream_t stream)
{
    const float* x = (const float*)d_in[0];
    const float* y = (const float*)d_in[1];
    float* out = (float*)d_out;

    // Ping-pong potential buffers in workspace: [4 slots][B][NPTS] each.
    const size_t potElems = (size_t)4 * BATCH * NPTS;
    float* P0 = (float*)d_ws;
    float* P1 = P0 + potElems;

    // Zero the initial potentials (h = a_log exactly at init; old = 0).
    hipMemsetAsync(P0, 0, potElems * sizeof(float), stream);

    // Epsilon schedule: [diam^p] + exp(arange(p ln diam, p ln blur, p ln scale)) + [blur^p]
    double epsl[16];
    int ne = 0;
    epsl[ne++] = 4.0;                       // diameter^2
    const double stop = 2.0 * log(0.05);
    const double step = 2.0 * log(0.5);
    for (double e = 2.0 * log(2.0); e > stop; e += step)
        epsl[ne++] = exp(e);                // 4, 1, 0.25, 0.0625, 0.015625, 0.00390625
    epsl[ne++] = 0.05 * 0.05;               // blur^2 = 0.0025

    float* src = P0;
    float* dst = P1;
    dim3 grid(NPTS / ROWS_PER_BLOCK, BATCH, 4);

    auto launch = [&](double eps, int avg) {
        float sigma  = (float)(M_LOG2E / eps);   // K=16, no k-dup
        float k2     = (float)(eps * M_LN2);
        float inv_k2 = (float)(1.0 / (eps * M_LN2));
        float rowc0  = (float)(eps * LOG_M);
        softmin_pass<<<grid, THREADS, 0, stream>>>(
            x, y, src, dst, sigma, k2, inv_k2, rowc0, avg);
        float* t = src; src = dst; dst = t;
    };

    launch(epsl[0], 0);                       // init (writes direct)
    for (int k = 0; k < ne; ++k)
        launch(epsl[k], 1);                   // damped symmetric Sinkhorn
    launch(epsl[ne - 1], 0);                  // final extrapolation (writes direct)

    reduce_out<<<dim3(BATCH), THREADS, 0, stream>>>(src, out);
}